// Round 1
// baseline (1113.244 us; speedup 1.0000x reference)
//
#include <hip/hip_runtime.h>
#include <hip/hip_bf16.h>

#define D 128
#define NGRAPH 64
#define SCAN_EPB 2048   // elements per scan block (256 thr * 8)

// ---------------- CSR build ----------------

__global__ __launch_bounds__(256) void k_count(const int* __restrict__ dst,
                                               int* __restrict__ deg, int E) {
    int i = blockIdx.x * blockDim.x + threadIdx.x;
    int stride = gridDim.x * blockDim.x;
    for (; i < E; i += stride) atomicAdd(&deg[dst[i]], 1);
}

__global__ __launch_bounds__(256) void k_scan_a(const int* __restrict__ deg,
                                                int* __restrict__ offs,
                                                int* __restrict__ bsum, int n) {
    __shared__ int sdata[256];
    int tid = threadIdx.x;
    int base = blockIdx.x * SCAN_EPB;
    int i0 = base + tid * 8;
    int vals[8];
    int s = 0;
#pragma unroll
    for (int j = 0; j < 8; ++j) {
        int i = i0 + j;
        int d = (i < n) ? deg[i] : 0;
        vals[j] = s;     // exclusive within thread
        s += d;
    }
    sdata[tid] = s;
    __syncthreads();
    // inclusive Hillis-Steele scan over 256 thread sums
    for (int off = 1; off < 256; off <<= 1) {
        int y = (tid >= off) ? sdata[tid - off] : 0;
        __syncthreads();
        sdata[tid] += y;
        __syncthreads();
    }
    int texcl = sdata[tid] - s;
#pragma unroll
    for (int j = 0; j < 8; ++j) {
        int i = i0 + j;
        if (i < n) offs[i] = texcl + vals[j];
    }
    if (tid == 255) bsum[blockIdx.x] = sdata[255];
}

__global__ void k_scan_b(int* bsum, int nb) {
    if (threadIdx.x == 0 && blockIdx.x == 0) {
        int run = 0;
        for (int b = 0; b < nb; ++b) { int t = bsum[b]; bsum[b] = run; run += t; }
    }
}

// offs += block base; cursor = offs; dinv = rsqrt(indeg+1)
__global__ __launch_bounds__(256) void k_finalize(int* __restrict__ offs,
                                                  const int* __restrict__ bsum,
                                                  int* __restrict__ cursor,
                                                  const int* __restrict__ deg,
                                                  float* __restrict__ dinv, int n) {
    int i = blockIdx.x * blockDim.x + threadIdx.x;
    if (i >= n) return;
    int o = offs[i] + bsum[i / SCAN_EPB];
    offs[i] = o;
    cursor[i] = o;
    dinv[i] = rsqrtf((float)(deg[i] + 1));
}

__global__ __launch_bounds__(256) void k_fill(const int* __restrict__ src,
                                              const int* __restrict__ dst,
                                              int* __restrict__ cursor,
                                              int* __restrict__ csr, int E) {
    int i = blockIdx.x * blockDim.x + threadIdx.x;
    int stride = gridDim.x * blockDim.x;
    for (; i < E; i += stride) {
        int d = dst[i];
        int idx = atomicAdd(&cursor[d], 1);
        csr[idx] = src[i];
    }
}

// ---------------- dense GEMM: H = X @ W  (M x 128 @ 128 x 128, fp32) ------

#define GBM 64
#define GBK 32
__global__ __launch_bounds__(256) void k_gemm128(const float* __restrict__ X,
                                                 const float* __restrict__ W,
                                                 float* __restrict__ H, int nrows) {
    __shared__ float xs[GBM][GBK + 1];
    __shared__ float ws[GBK][D];
    int tid = threadIdx.x;
    int tc = tid & 31;   // col group: cols tc*4 .. +3
    int tr = tid >> 5;   // row group: rows tr*8 .. +7
    int m0 = blockIdx.x * GBM;
    float acc[8][4] = {};
    for (int kk = 0; kk < D; kk += GBK) {
        for (int i = tid; i < GBM * GBK; i += 256) {
            int r = i >> 5, c = i & 31;
            int gr = m0 + r;
            xs[r][c] = (gr < nrows) ? X[(size_t)gr * D + kk + c] : 0.f;
        }
        for (int i = tid; i < GBK * D; i += 256) {
            int r = i >> 7, c = i & 127;
            ws[r][c] = W[(size_t)(kk + r) * D + c];
        }
        __syncthreads();
#pragma unroll 4
        for (int k = 0; k < GBK; ++k) {
            float a[8];
#pragma unroll
            for (int ri = 0; ri < 8; ++ri) a[ri] = xs[tr * 8 + ri][k];
            float4 bv = *(const float4*)&ws[k][tc * 4];
            float b[4] = {bv.x, bv.y, bv.z, bv.w};
#pragma unroll
            for (int ri = 0; ri < 8; ++ri)
#pragma unroll
                for (int ci = 0; ci < 4; ++ci)
                    acc[ri][ci] += a[ri] * b[ci];
        }
        __syncthreads();
    }
#pragma unroll
    for (int ri = 0; ri < 8; ++ri) {
        int gr = m0 + tr * 8 + ri;
        if (gr < nrows) {
            float4 v = make_float4(acc[ri][0], acc[ri][1], acc[ri][2], acc[ri][3]);
            *(float4*)&H[(size_t)gr * D + tc * 4] = v;
        }
    }
}

// ---------------- aggregation: Out[v] = sum_{e: dst=v} H[src]*norm + self + bias

__global__ __launch_bounds__(256) void k_agg(const float* __restrict__ H,
                                             const int* __restrict__ offs,
                                             const int* __restrict__ csr,
                                             const float* __restrict__ dinv,
                                             const float* __restrict__ bias,
                                             float* __restrict__ Out,
                                             int n, int E, int relu) {
    int wid = threadIdx.x >> 6;
    int lane = threadIdx.x & 63;
    int v = blockIdx.x * 4 + wid;
    if (v >= n) return;
    float dv = dinv[v];
    // self loop: norm = dv*dv
    float2 acc = *(const float2*)(H + (size_t)v * D + lane * 2);
    float dv2 = dv * dv;
    acc.x *= dv2; acc.y *= dv2;
    int e = offs[v];
    int eE = (v == n - 1) ? E : offs[v + 1];
    for (; e + 1 < eE; e += 2) {
        int s0 = csr[e], s1 = csr[e + 1];
        float w0 = dinv[s0] * dv;
        float w1 = dinv[s1] * dv;
        float2 h0 = *(const float2*)(H + (size_t)s0 * D + lane * 2);
        float2 h1 = *(const float2*)(H + (size_t)s1 * D + lane * 2);
        acc.x += h0.x * w0; acc.y += h0.y * w0;
        acc.x += h1.x * w1; acc.y += h1.y * w1;
    }
    if (e < eE) {
        int s0 = csr[e];
        float w0 = dinv[s0] * dv;
        float2 h0 = *(const float2*)(H + (size_t)s0 * D + lane * 2);
        acc.x += h0.x * w0; acc.y += h0.y * w0;
    }
    float2 b = ((const float2*)bias)[lane];
    acc.x += b.x; acc.y += b.y;
    if (relu) { acc.x = fmaxf(acc.x, 0.f); acc.y = fmaxf(acc.y, 0.f); }
    *(float2*)(Out + (size_t)v * D + lane * 2) = acc;
}

// ---------------- mean pool (batch sorted) + classifier ----------------

__global__ __launch_bounds__(256) void k_pool(const float* __restrict__ H,
                                              const int* __restrict__ batch,
                                              float* __restrict__ sums,
                                              int* __restrict__ cnt, int n) {
    int wid = threadIdx.x >> 6;
    int lane = threadIdx.x & 63;
    int chunk = blockIdx.x * 4 + wid;   // 128 nodes per wave
    int v0 = chunk * 128;
    if (v0 >= n) return;
    int vend = min(v0 + 128, n);
    int gcur = batch[v0];
    float2 acc = {0.f, 0.f};
    int count = 0;
    for (int v = v0; v < vend; ++v) {
        int g = batch[v];
        if (g != gcur) {
            atomicAdd(&sums[gcur * D + lane * 2], acc.x);
            atomicAdd(&sums[gcur * D + lane * 2 + 1], acc.y);
            if (lane == 0) atomicAdd(&cnt[gcur], count);
            acc.x = acc.y = 0.f; count = 0; gcur = g;
        }
        float2 hv = *(const float2*)(H + (size_t)v * D + lane * 2);
        acc.x += hv.x; acc.y += hv.y;
        ++count;
    }
    atomicAdd(&sums[gcur * D + lane * 2], acc.x);
    atomicAdd(&sums[gcur * D + lane * 2 + 1], acc.y);
    if (lane == 0) atomicAdd(&cnt[gcur], count);
}

__global__ void k_classify(const float* __restrict__ sums, const int* __restrict__ cnt,
                           const float* __restrict__ Wc, const float* __restrict__ bc,
                           float* __restrict__ out) {
    int t = threadIdx.x;         // 128 threads: t = g*2 + c
    if (t >= NGRAPH * 2) return;
    int g = t >> 1, c = t & 1;
    float inv = 1.0f / fmaxf((float)cnt[g], 1.0f);
    float acc = 0.f;
    for (int k = 0; k < D; ++k) acc += sums[g * D + k] * Wc[k * 2 + c];
    out[t] = acc * inv + bc[c];
}

// ---------------- launch ----------------

extern "C" void kernel_launch(void* const* d_in, const int* in_sizes, int n_in,
                              void* d_out, int out_size, void* d_ws, size_t ws_size,
                              hipStream_t stream) {
    const float* x    = (const float*)d_in[0];
    const int*   ei   = (const int*)d_in[1];
    const int*   batch= (const int*)d_in[2];
    const float* W1   = (const float*)d_in[3];
    const float* b1   = (const float*)d_in[4];
    const float* W2   = (const float*)d_in[5];
    const float* b2   = (const float*)d_in[6];
    const float* Wc   = (const float*)d_in[7];
    const float* bc   = (const float*)d_in[8];

    const int n = in_sizes[0] / D;       // 100000
    const int E = in_sizes[1] / 2;       // 3200000
    const int* src = ei;
    const int* dst = ei + E;

    // workspace carve-up (256B aligned)
    char* ws = (char*)d_ws;
    size_t off = 0;
    auto carve = [&](size_t bytes) -> char* {
        char* p = ws + off;
        off = (off + bytes + 255) & ~(size_t)255;
        return p;
    };
    float* bufA   = (float*)carve((size_t)n * D * 4);
    float* bufB   = (float*)carve((size_t)n * D * 4);
    int*   csr    = (int*)  carve((size_t)E * 4);
    int*   deg    = (int*)  carve((size_t)n * 4);
    int*   offs   = (int*)  carve((size_t)n * 4);
    int*   cursor = (int*)  carve((size_t)n * 4);
    float* dinv   = (float*)carve((size_t)n * 4);
    int*   bsum   = (int*)  carve(256 * 4);
    float* sums   = (float*)carve((size_t)NGRAPH * D * 4 + NGRAPH * 4);
    int*   cnt    = (int*)(sums + NGRAPH * D);

    const int nb = (n + SCAN_EPB - 1) / SCAN_EPB;

    hipMemsetAsync(deg, 0, (size_t)n * 4, stream);
    hipMemsetAsync(sums, 0, (size_t)NGRAPH * D * 4 + NGRAPH * 4, stream);

    k_count<<<2048, 256, 0, stream>>>(dst, deg, E);
    k_scan_a<<<nb, 256, 0, stream>>>(deg, offs, bsum, n);
    k_scan_b<<<1, 64, 0, stream>>>(bsum, nb);
    k_finalize<<<(n + 255) / 256, 256, 0, stream>>>(offs, bsum, cursor, deg, dinv, n);
    k_fill<<<2048, 256, 0, stream>>>(src, dst, cursor, csr, E);

    // layer 1: h = relu(agg(x @ W1) + b1)
    k_gemm128<<<(n + GBM - 1) / GBM, 256, 0, stream>>>(x, W1, bufA, n);
    k_agg<<<(n + 3) / 4, 256, 0, stream>>>(bufA, offs, csr, dinv, b1, bufB, n, E, 1);
    // layer 2: h2 = agg(h1 @ W2) + b2
    k_gemm128<<<(n + GBM - 1) / GBM, 256, 0, stream>>>(bufB, W2, bufA, n);
    k_agg<<<(n + 3) / 4, 256, 0, stream>>>(bufA, offs, csr, dinv, b2, bufB, n, E, 0);

    // pool + classify
    k_pool<<<(n + 511) / 512, 256, 0, stream>>>(bufB, batch, sums, cnt, n);
    k_classify<<<1, 128, 0, stream>>>(sums, cnt, Wc, bc, (float*)d_out);
}

// Round 2
// 979.757 us; speedup vs baseline: 1.1362x; 1.1362x over previous
//
#include <hip/hip_runtime.h>
#include <hip/hip_bf16.h>

#define D 128
#define NGRAPH 64
#define SCAN_EPB 2048   // elements per scan block (256 thr * 8)
#define CHUNK 4096      // edges staged in LDS per block in k_fill2
#define BSHIFT 13       // dst-bucket = dst >> 13  (8192 nodes/bucket, ~1MB csr window)

// ---------------- CSR build ----------------

// rank[i] = running index of edge i within its dst segment; deg accumulates indegree
__global__ __launch_bounds__(256) void k_count(const int* __restrict__ dst,
                                               int* __restrict__ deg,
                                               int* __restrict__ rank, int E) {
    int i = blockIdx.x * blockDim.x + threadIdx.x;
    int stride = gridDim.x * blockDim.x;
    for (; i < E; i += stride) {
        int d = __builtin_nontemporal_load(&dst[i]);
        int r = atomicAdd(&deg[d], 1);
        __builtin_nontemporal_store(r, &rank[i]);
    }
}

__global__ __launch_bounds__(256) void k_scan_a(const int* __restrict__ deg,
                                                int* __restrict__ offs,
                                                int* __restrict__ bsum, int n) {
    __shared__ int sdata[256];
    int tid = threadIdx.x;
    int base = blockIdx.x * SCAN_EPB;
    int i0 = base + tid * 8;
    int vals[8];
    int s = 0;
#pragma unroll
    for (int j = 0; j < 8; ++j) {
        int i = i0 + j;
        int d = (i < n) ? deg[i] : 0;
        vals[j] = s;     // exclusive within thread
        s += d;
    }
    sdata[tid] = s;
    __syncthreads();
    for (int off = 1; off < 256; off <<= 1) {
        int y = (tid >= off) ? sdata[tid - off] : 0;
        __syncthreads();
        sdata[tid] += y;
        __syncthreads();
    }
    int texcl = sdata[tid] - s;
#pragma unroll
    for (int j = 0; j < 8; ++j) {
        int i = i0 + j;
        if (i < n) offs[i] = texcl + vals[j];
    }
    if (tid == 255) bsum[blockIdx.x] = sdata[255];
}

__global__ void k_scan_b(int* bsum, int nb) {
    if (threadIdx.x == 0 && blockIdx.x == 0) {
        int run = 0;
        for (int b = 0; b < nb; ++b) { int t = bsum[b]; bsum[b] = run; run += t; }
    }
}

// offs += block base; dinv = rsqrt(indeg+1)
__global__ __launch_bounds__(256) void k_finalize(int* __restrict__ offs,
                                                  const int* __restrict__ bsum,
                                                  const int* __restrict__ deg,
                                                  float* __restrict__ dinv, int n) {
    int i = blockIdx.x * blockDim.x + threadIdx.x;
    if (i >= n) return;
    offs[i] = offs[i] + bsum[i / SCAN_EPB];
    dinv[i] = rsqrtf((float)(deg[i] + 1));
}

// bucketed, atomic-free CSR fill: pass p writes only dst-bucket p so the live
// csr write window (~1MB) stays L2-resident and lines are evicted full.
__global__ __launch_bounds__(256) void k_fill2(const int* __restrict__ src,
                                               const int* __restrict__ dst,
                                               const int* __restrict__ rank,
                                               const int* __restrict__ offs,
                                               int* __restrict__ csr,
                                               int E, int nbuckets) {
    __shared__ int sdst[CHUNK];
    __shared__ int ssrc[CHUNK];
    __shared__ int srank[CHUNK];
    int base = blockIdx.x * CHUNK;
    int cnt = min(CHUNK, E - base);
    for (int j = threadIdx.x; j < cnt; j += 256) {
        sdst[j]  = __builtin_nontemporal_load(&dst[base + j]);
        ssrc[j]  = __builtin_nontemporal_load(&src[base + j]);
        srank[j] = __builtin_nontemporal_load(&rank[base + j]);
    }
    __syncthreads();
    for (int p = 0; p < nbuckets; ++p) {
        for (int j = threadIdx.x; j < cnt; j += 256) {
            int d = sdst[j];
            if ((d >> BSHIFT) == p) {
                csr[offs[d] + srank[j]] = ssrc[j];
            }
        }
        __syncthreads();   // keep the block's waves in lockstep per bucket
    }
}

// ---------------- dense GEMM: H = X @ W  (M x 128 @ 128 x 128, fp32) ------

#define GBM 64
#define GBK 32
__global__ __launch_bounds__(256) void k_gemm128(const float* __restrict__ X,
                                                 const float* __restrict__ W,
                                                 float* __restrict__ H, int nrows) {
    __shared__ float xs[GBM][GBK + 1];
    __shared__ float ws[GBK][D];
    int tid = threadIdx.x;
    int tc = tid & 31;   // col group: cols tc*4 .. +3
    int tr = tid >> 5;   // row group: rows tr*8 .. +7
    int m0 = blockIdx.x * GBM;
    float acc[8][4] = {};
    for (int kk = 0; kk < D; kk += GBK) {
        for (int i = tid; i < GBM * GBK; i += 256) {
            int r = i >> 5, c = i & 31;
            int gr = m0 + r;
            xs[r][c] = (gr < nrows) ? X[(size_t)gr * D + kk + c] : 0.f;
        }
        for (int i = tid; i < GBK * D; i += 256) {
            int r = i >> 7, c = i & 127;
            ws[r][c] = W[(size_t)(kk + r) * D + c];
        }
        __syncthreads();
#pragma unroll 4
        for (int k = 0; k < GBK; ++k) {
            float a[8];
#pragma unroll
            for (int ri = 0; ri < 8; ++ri) a[ri] = xs[tr * 8 + ri][k];
            float4 bv = *(const float4*)&ws[k][tc * 4];
            float b[4] = {bv.x, bv.y, bv.z, bv.w};
#pragma unroll
            for (int ri = 0; ri < 8; ++ri)
#pragma unroll
                for (int ci = 0; ci < 4; ++ci)
                    acc[ri][ci] += a[ri] * b[ci];
        }
        __syncthreads();
    }
#pragma unroll
    for (int ri = 0; ri < 8; ++ri) {
        int gr = m0 + tr * 8 + ri;
        if (gr < nrows) {
            float4 v = make_float4(acc[ri][0], acc[ri][1], acc[ri][2], acc[ri][3]);
            *(float4*)&H[(size_t)gr * D + tc * 4] = v;
        }
    }
}

// ---------------- aggregation: Out[v] = sum_{e: dst=v} H[src]*norm + self + bias

__global__ __launch_bounds__(256) void k_agg(const float* __restrict__ H,
                                             const int* __restrict__ offs,
                                             const int* __restrict__ csr,
                                             const float* __restrict__ dinv,
                                             const float* __restrict__ bias,
                                             float* __restrict__ Out,
                                             int n, int E, int relu) {
    int wid = threadIdx.x >> 6;
    int lane = threadIdx.x & 63;
    int v = blockIdx.x * 4 + wid;
    if (v >= n) return;
    float dv = dinv[v];
    // self loop: norm = dv*dv
    float2 acc = *(const float2*)(H + (size_t)v * D + lane * 2);
    float dv2 = dv * dv;
    acc.x *= dv2; acc.y *= dv2;
    int e = offs[v];
    int eE = (v == n - 1) ? E : offs[v + 1];
    for (; e + 1 < eE; e += 2) {
        int s0 = csr[e], s1 = csr[e + 1];
        float w0 = dinv[s0] * dv;
        float w1 = dinv[s1] * dv;
        float2 h0 = *(const float2*)(H + (size_t)s0 * D + lane * 2);
        float2 h1 = *(const float2*)(H + (size_t)s1 * D + lane * 2);
        acc.x += h0.x * w0; acc.y += h0.y * w0;
        acc.x += h1.x * w1; acc.y += h1.y * w1;
    }
    if (e < eE) {
        int s0 = csr[e];
        float w0 = dinv[s0] * dv;
        float2 h0 = *(const float2*)(H + (size_t)s0 * D + lane * 2);
        acc.x += h0.x * w0; acc.y += h0.y * w0;
    }
    float2 b = ((const float2*)bias)[lane];
    acc.x += b.x; acc.y += b.y;
    if (relu) { acc.x = fmaxf(acc.x, 0.f); acc.y = fmaxf(acc.y, 0.f); }
    *(float2*)(Out + (size_t)v * D + lane * 2) = acc;
}

// ---------------- mean pool (batch sorted) + classifier ----------------

__global__ __launch_bounds__(256) void k_pool(const float* __restrict__ H,
                                              const int* __restrict__ batch,
                                              float* __restrict__ sums,
                                              int* __restrict__ cnt, int n) {
    int wid = threadIdx.x >> 6;
    int lane = threadIdx.x & 63;
    int chunk = blockIdx.x * 4 + wid;   // 128 nodes per wave
    int v0 = chunk * 128;
    if (v0 >= n) return;
    int vend = min(v0 + 128, n);
    int gcur = batch[v0];
    float2 acc = {0.f, 0.f};
    int count = 0;
    for (int v = v0; v < vend; ++v) {
        int g = batch[v];
        if (g != gcur) {
            atomicAdd(&sums[gcur * D + lane * 2], acc.x);
            atomicAdd(&sums[gcur * D + lane * 2 + 1], acc.y);
            if (lane == 0) atomicAdd(&cnt[gcur], count);
            acc.x = acc.y = 0.f; count = 0; gcur = g;
        }
        float2 hv = *(const float2*)(H + (size_t)v * D + lane * 2);
        acc.x += hv.x; acc.y += hv.y;
        ++count;
    }
    atomicAdd(&sums[gcur * D + lane * 2], acc.x);
    atomicAdd(&sums[gcur * D + lane * 2 + 1], acc.y);
    if (lane == 0) atomicAdd(&cnt[gcur], count);
}

__global__ void k_classify(const float* __restrict__ sums, const int* __restrict__ cnt,
                           const float* __restrict__ Wc, const float* __restrict__ bc,
                           float* __restrict__ out) {
    int t = threadIdx.x;         // 128 threads: t = g*2 + c
    if (t >= NGRAPH * 2) return;
    int g = t >> 1, c = t & 1;
    float inv = 1.0f / fmaxf((float)cnt[g], 1.0f);
    float acc = 0.f;
    for (int k = 0; k < D; ++k) acc += sums[g * D + k] * Wc[k * 2 + c];
    out[t] = acc * inv + bc[c];
}

// ---------------- launch ----------------

extern "C" void kernel_launch(void* const* d_in, const int* in_sizes, int n_in,
                              void* d_out, int out_size, void* d_ws, size_t ws_size,
                              hipStream_t stream) {
    const float* x    = (const float*)d_in[0];
    const int*   ei   = (const int*)d_in[1];
    const int*   batch= (const int*)d_in[2];
    const float* W1   = (const float*)d_in[3];
    const float* b1   = (const float*)d_in[4];
    const float* W2   = (const float*)d_in[5];
    const float* b2   = (const float*)d_in[6];
    const float* Wc   = (const float*)d_in[7];
    const float* bc   = (const float*)d_in[8];

    const int n = in_sizes[0] / D;       // 100000
    const int E = in_sizes[1] / 2;       // 3200000
    const int* src = ei;
    const int* dst = ei + E;

    // workspace carve-up (256B aligned)
    char* ws = (char*)d_ws;
    size_t off = 0;
    auto carve = [&](size_t bytes) -> char* {
        char* p = ws + off;
        off = (off + bytes + 255) & ~(size_t)255;
        return p;
    };
    float* bufA   = (float*)carve((size_t)n * D * 4);
    float* bufB   = (float*)carve((size_t)n * D * 4);
    int*   csr    = (int*)  carve((size_t)E * 4);
    int*   rank   = (int*)  carve((size_t)E * 4);
    int*   deg    = (int*)  carve((size_t)n * 4);
    int*   offs   = (int*)  carve((size_t)n * 4);
    float* dinv   = (float*)carve((size_t)n * 4);
    int*   bsum   = (int*)  carve(256 * 4);
    float* sums   = (float*)carve((size_t)NGRAPH * D * 4 + NGRAPH * 4);
    int*   cnt    = (int*)(sums + NGRAPH * D);

    const int nb = (n + SCAN_EPB - 1) / SCAN_EPB;
    const int nbuckets = (n >> BSHIFT) + 1;     // 13 for n=100000

    hipMemsetAsync(deg, 0, (size_t)n * 4, stream);
    hipMemsetAsync(sums, 0, (size_t)NGRAPH * D * 4 + NGRAPH * 4, stream);

    k_count<<<2048, 256, 0, stream>>>(dst, deg, rank, E);
    k_scan_a<<<nb, 256, 0, stream>>>(deg, offs, bsum, n);
    k_scan_b<<<1, 64, 0, stream>>>(bsum, nb);
    k_finalize<<<(n + 255) / 256, 256, 0, stream>>>(offs, bsum, deg, dinv, n);
    k_fill2<<<(E + CHUNK - 1) / CHUNK, 256, 0, stream>>>(src, dst, rank, offs, csr, E, nbuckets);

    // layer 1: h = relu(agg(x @ W1) + b1)
    k_gemm128<<<(n + GBM - 1) / GBM, 256, 0, stream>>>(x, W1, bufA, n);
    k_agg<<<(n + 3) / 4, 256, 0, stream>>>(bufA, offs, csr, dinv, b1, bufB, n, E, 1);
    // layer 2: h2 = agg(h1 @ W2) + b2
    k_gemm128<<<(n + GBM - 1) / GBM, 256, 0, stream>>>(bufB, W2, bufA, n);
    k_agg<<<(n + 3) / 4, 256, 0, stream>>>(bufA, offs, csr, dinv, b2, bufB, n, E, 0);

    // pool + classify
    k_pool<<<(n + 511) / 512, 256, 0, stream>>>(bufB, batch, sums, cnt, n);
    k_classify<<<1, 128, 0, stream>>>(sums, cnt, Wc, bc, (float*)d_out);
}

// Round 3
// 708.158 us; speedup vs baseline: 1.5720x; 1.3835x over previous
//
#include <hip/hip_runtime.h>
#include <hip/hip_bf16.h>

#define D 128
#define NGRAPH 64
#define SCAN_EPB 2048   // elements per scan block (256 thr * 8)
#define CHUNK 4096      // edges staged in LDS per block in k_fill2
#define BSHIFT 13       // dst-bucket = dst >> 13  (8192 nodes/bucket, ~1MB csr window)

__device__ __forceinline__ unsigned short f2bf(float f) {
    union { float f; unsigned int i; } u; u.f = f;
    unsigned int r = u.i + 0x7fffu + ((u.i >> 16) & 1u);   // round-to-nearest-even
    return (unsigned short)(r >> 16);
}
__device__ __forceinline__ float2 bf2_to_f2(unsigned int u) {
    union { unsigned int i; float f; } a, b;
    a.i = u << 16;            // low ushort  = element 0
    b.i = u & 0xffff0000u;    // high ushort = element 1
    return make_float2(a.f, b.f);
}

// ---------------- CSR build ----------------

// rank[i] = running index of edge i within its dst segment; deg accumulates indegree
__global__ __launch_bounds__(256) void k_count(const int* __restrict__ dst,
                                               int* __restrict__ deg,
                                               int* __restrict__ rank, int E) {
    int i = blockIdx.x * blockDim.x + threadIdx.x;
    int stride = gridDim.x * blockDim.x;
    for (; i < E; i += stride) {
        int d = __builtin_nontemporal_load(&dst[i]);
        int r = atomicAdd(&deg[d], 1);
        __builtin_nontemporal_store(r, &rank[i]);
    }
}

__global__ __launch_bounds__(256) void k_scan_a(const int* __restrict__ deg,
                                                int* __restrict__ offs,
                                                int* __restrict__ bsum, int n) {
    __shared__ int sdata[256];
    int tid = threadIdx.x;
    int base = blockIdx.x * SCAN_EPB;
    int i0 = base + tid * 8;
    int vals[8];
    int s = 0;
#pragma unroll
    for (int j = 0; j < 8; ++j) {
        int i = i0 + j;
        int d = (i < n) ? deg[i] : 0;
        vals[j] = s;     // exclusive within thread
        s += d;
    }
    sdata[tid] = s;
    __syncthreads();
    for (int off = 1; off < 256; off <<= 1) {
        int y = (tid >= off) ? sdata[tid - off] : 0;
        __syncthreads();
        sdata[tid] += y;
        __syncthreads();
    }
    int texcl = sdata[tid] - s;
#pragma unroll
    for (int j = 0; j < 8; ++j) {
        int i = i0 + j;
        if (i < n) offs[i] = texcl + vals[j];
    }
    if (tid == 255) bsum[blockIdx.x] = sdata[255];
}

__global__ void k_scan_b(int* bsum, int nb) {
    if (threadIdx.x == 0 && blockIdx.x == 0) {
        int run = 0;
        for (int b = 0; b < nb; ++b) { int t = bsum[b]; bsum[b] = run; run += t; }
    }
}

// offs += block base; dinv = rsqrt(indeg+1)
__global__ __launch_bounds__(256) void k_finalize(int* __restrict__ offs,
                                                  const int* __restrict__ bsum,
                                                  const int* __restrict__ deg,
                                                  float* __restrict__ dinv, int n) {
    int i = blockIdx.x * blockDim.x + threadIdx.x;
    if (i >= n) return;
    offs[i] = offs[i] + bsum[i / SCAN_EPB];
    dinv[i] = rsqrtf((float)(deg[i] + 1));
}

// bucketed, atomic-free CSR fill: pass p writes only dst-bucket p so the live
// csr write window (~1MB) stays L2-resident and lines are evicted full.
__global__ __launch_bounds__(256) void k_fill2(const int* __restrict__ src,
                                               const int* __restrict__ dst,
                                               const int* __restrict__ rank,
                                               const int* __restrict__ offs,
                                               int* __restrict__ csr,
                                               int E, int nbuckets) {
    __shared__ int sdst[CHUNK];
    __shared__ int ssrc[CHUNK];
    __shared__ int srank[CHUNK];
    int base = blockIdx.x * CHUNK;
    int cnt = min(CHUNK, E - base);
    for (int j = threadIdx.x; j < cnt; j += 256) {
        sdst[j]  = __builtin_nontemporal_load(&dst[base + j]);
        ssrc[j]  = __builtin_nontemporal_load(&src[base + j]);
        srank[j] = __builtin_nontemporal_load(&rank[base + j]);
    }
    __syncthreads();
    for (int p = 0; p < nbuckets; ++p) {
        for (int j = threadIdx.x; j < cnt; j += 256) {
            int d = sdst[j];
            if ((d >> BSHIFT) == p) {
                csr[offs[d] + srank[j]] = ssrc[j];
            }
        }
        __syncthreads();   // keep the block's waves in lockstep per bucket
    }
}

// ---------------- dense GEMM: H = X @ W  (M x 128 @ 128 x 128, fp32 in, bf16 out)

#define GBM 64
#define GBK 32
__global__ __launch_bounds__(256) void k_gemm128(const float* __restrict__ X,
                                                 const float* __restrict__ W,
                                                 unsigned short* __restrict__ H, int nrows) {
    __shared__ float xs[GBM][GBK + 1];
    __shared__ float ws[GBK][D];
    int tid = threadIdx.x;
    int tc = tid & 31;   // col group: cols tc*4 .. +3
    int tr = tid >> 5;   // row group: rows tr*8 .. +7
    int m0 = blockIdx.x * GBM;
    float acc[8][4] = {};
    for (int kk = 0; kk < D; kk += GBK) {
        for (int i = tid; i < GBM * GBK; i += 256) {
            int r = i >> 5, c = i & 31;
            int gr = m0 + r;
            xs[r][c] = (gr < nrows) ? X[(size_t)gr * D + kk + c] : 0.f;
        }
        for (int i = tid; i < GBK * D; i += 256) {
            int r = i >> 7, c = i & 127;
            ws[r][c] = W[(size_t)(kk + r) * D + c];
        }
        __syncthreads();
#pragma unroll 4
        for (int k = 0; k < GBK; ++k) {
            float a[8];
#pragma unroll
            for (int ri = 0; ri < 8; ++ri) a[ri] = xs[tr * 8 + ri][k];
            float4 bv = *(const float4*)&ws[k][tc * 4];
            float b[4] = {bv.x, bv.y, bv.z, bv.w};
#pragma unroll
            for (int ri = 0; ri < 8; ++ri)
#pragma unroll
                for (int ci = 0; ci < 4; ++ci)
                    acc[ri][ci] += a[ri] * b[ci];
        }
        __syncthreads();
    }
#pragma unroll
    for (int ri = 0; ri < 8; ++ri) {
        int gr = m0 + tr * 8 + ri;
        if (gr < nrows) {
            ushort4 v;
            v.x = f2bf(acc[ri][0]); v.y = f2bf(acc[ri][1]);
            v.z = f2bf(acc[ri][2]); v.w = f2bf(acc[ri][3]);
            *(ushort4*)&H[(size_t)gr * D + tc * 4] = v;
        }
    }
}

// ---------------- aggregation: Out[v] = sum_{e: dst=v} H[src]*norm + self + bias
// H is bf16 [n][128]; accumulate fp32; Out fp32.

__global__ __launch_bounds__(256) void k_agg(const unsigned short* __restrict__ H,
                                             const int* __restrict__ offs,
                                             const int* __restrict__ csr,
                                             const float* __restrict__ dinv,
                                             const float* __restrict__ bias,
                                             float* __restrict__ Out,
                                             int n, int E, int relu) {
    int wid = threadIdx.x >> 6;
    int lane = threadIdx.x & 63;
    int v = blockIdx.x * 4 + wid;
    if (v >= n) return;
    float dv = dinv[v];
    // self loop: norm = dv*dv
    unsigned us = *(const unsigned*)(H + (size_t)v * D + lane * 2);
    float2 hs = bf2_to_f2(us);
    float dv2 = dv * dv;
    float2 acc = make_float2(hs.x * dv2, hs.y * dv2);
    int e = offs[v];
    int eE = (v == n - 1) ? E : offs[v + 1];
    for (; e + 3 < eE; e += 4) {
        int s0 = csr[e], s1 = csr[e + 1], s2 = csr[e + 2], s3 = csr[e + 3];
        unsigned u0 = *(const unsigned*)(H + (size_t)s0 * D + lane * 2);
        unsigned u1 = *(const unsigned*)(H + (size_t)s1 * D + lane * 2);
        unsigned u2 = *(const unsigned*)(H + (size_t)s2 * D + lane * 2);
        unsigned u3 = *(const unsigned*)(H + (size_t)s3 * D + lane * 2);
        float w0 = dinv[s0] * dv, w1 = dinv[s1] * dv;
        float w2 = dinv[s2] * dv, w3 = dinv[s3] * dv;
        float2 h0 = bf2_to_f2(u0), h1 = bf2_to_f2(u1);
        float2 h2 = bf2_to_f2(u2), h3 = bf2_to_f2(u3);
        acc.x += h0.x * w0; acc.y += h0.y * w0;
        acc.x += h1.x * w1; acc.y += h1.y * w1;
        acc.x += h2.x * w2; acc.y += h2.y * w2;
        acc.x += h3.x * w3; acc.y += h3.y * w3;
    }
    for (; e < eE; ++e) {
        int s0 = csr[e];
        float w0 = dinv[s0] * dv;
        unsigned u0 = *(const unsigned*)(H + (size_t)s0 * D + lane * 2);
        float2 h0 = bf2_to_f2(u0);
        acc.x += h0.x * w0; acc.y += h0.y * w0;
    }
    float2 b = ((const float2*)bias)[lane];
    acc.x += b.x; acc.y += b.y;
    if (relu) { acc.x = fmaxf(acc.x, 0.f); acc.y = fmaxf(acc.y, 0.f); }
    *(float2*)(Out + (size_t)v * D + lane * 2) = acc;
}

// ---------------- mean pool (batch sorted) + classifier ----------------

__global__ __launch_bounds__(256) void k_pool(const float* __restrict__ H,
                                              const int* __restrict__ batch,
                                              float* __restrict__ sums,
                                              int* __restrict__ cnt, int n) {
    int wid = threadIdx.x >> 6;
    int lane = threadIdx.x & 63;
    int chunk = blockIdx.x * 4 + wid;   // 128 nodes per wave
    int v0 = chunk * 128;
    if (v0 >= n) return;
    int vend = min(v0 + 128, n);
    int gcur = batch[v0];
    float2 acc = {0.f, 0.f};
    int count = 0;
    for (int v = v0; v < vend; ++v) {
        int g = batch[v];
        if (g != gcur) {
            atomicAdd(&sums[gcur * D + lane * 2], acc.x);
            atomicAdd(&sums[gcur * D + lane * 2 + 1], acc.y);
            if (lane == 0) atomicAdd(&cnt[gcur], count);
            acc.x = acc.y = 0.f; count = 0; gcur = g;
        }
        float2 hv = *(const float2*)(H + (size_t)v * D + lane * 2);
        acc.x += hv.x; acc.y += hv.y;
        ++count;
    }
    atomicAdd(&sums[gcur * D + lane * 2], acc.x);
    atomicAdd(&sums[gcur * D + lane * 2 + 1], acc.y);
    if (lane == 0) atomicAdd(&cnt[gcur], count);
}

__global__ void k_classify(const float* __restrict__ sums, const int* __restrict__ cnt,
                           const float* __restrict__ Wc, const float* __restrict__ bc,
                           float* __restrict__ out) {
    int t = threadIdx.x;         // 128 threads: t = g*2 + c
    if (t >= NGRAPH * 2) return;
    int g = t >> 1, c = t & 1;
    float inv = 1.0f / fmaxf((float)cnt[g], 1.0f);
    float acc = 0.f;
    for (int k = 0; k < D; ++k) acc += sums[g * D + k] * Wc[k * 2 + c];
    out[t] = acc * inv + bc[c];
}

// ---------------- launch ----------------

extern "C" void kernel_launch(void* const* d_in, const int* in_sizes, int n_in,
                              void* d_out, int out_size, void* d_ws, size_t ws_size,
                              hipStream_t stream) {
    const float* x    = (const float*)d_in[0];
    const int*   ei   = (const int*)d_in[1];
    const int*   batch= (const int*)d_in[2];
    const float* W1   = (const float*)d_in[3];
    const float* b1   = (const float*)d_in[4];
    const float* W2   = (const float*)d_in[5];
    const float* b2   = (const float*)d_in[6];
    const float* Wc   = (const float*)d_in[7];
    const float* bc   = (const float*)d_in[8];

    const int n = in_sizes[0] / D;       // 100000
    const int E = in_sizes[1] / 2;       // 3200000
    const int* src = ei;
    const int* dst = ei + E;

    // workspace carve-up (256B aligned)
    char* ws = (char*)d_ws;
    size_t off = 0;
    auto carve = [&](size_t bytes) -> char* {
        char* p = ws + off;
        off = (off + bytes + 255) & ~(size_t)255;
        return p;
    };
    unsigned short* bufBF = (unsigned short*)carve((size_t)n * D * 2);  // GEMM out (bf16)
    float* bufB   = (float*)carve((size_t)n * D * 4);                   // agg out (fp32)
    int*   csr    = (int*)  carve((size_t)E * 4);
    int*   rank   = (int*)  carve((size_t)E * 4);
    int*   deg    = (int*)  carve((size_t)n * 4);
    int*   offs   = (int*)  carve((size_t)n * 4);
    float* dinv   = (float*)carve((size_t)n * 4);
    int*   bsum   = (int*)  carve(256 * 4);
    float* sums   = (float*)carve((size_t)NGRAPH * D * 4 + NGRAPH * 4);
    int*   cnt    = (int*)(sums + NGRAPH * D);

    const int nb = (n + SCAN_EPB - 1) / SCAN_EPB;
    const int nbuckets = (n >> BSHIFT) + 1;     // 13 for n=100000

    hipMemsetAsync(deg, 0, (size_t)n * 4, stream);
    hipMemsetAsync(sums, 0, (size_t)NGRAPH * D * 4 + NGRAPH * 4, stream);

    k_count<<<2048, 256, 0, stream>>>(dst, deg, rank, E);
    k_scan_a<<<nb, 256, 0, stream>>>(deg, offs, bsum, n);
    k_scan_b<<<1, 64, 0, stream>>>(bsum, nb);
    k_finalize<<<(n + 255) / 256, 256, 0, stream>>>(offs, bsum, deg, dinv, n);
    k_fill2<<<(E + CHUNK - 1) / CHUNK, 256, 0, stream>>>(src, dst, rank, offs, csr, E, nbuckets);

    // layer 1: h = relu(agg(x @ W1) + b1)
    k_gemm128<<<(n + GBM - 1) / GBM, 256, 0, stream>>>(x, W1, bufBF, n);
    k_agg<<<(n + 3) / 4, 256, 0, stream>>>(bufBF, offs, csr, dinv, b1, bufB, n, E, 1);
    // layer 2: h2 = agg(h1 @ W2) + b2
    k_gemm128<<<(n + GBM - 1) / GBM, 256, 0, stream>>>(bufB, W2, bufBF, n);
    k_agg<<<(n + 3) / 4, 256, 0, stream>>>(bufBF, offs, csr, dinv, b2, bufB, n, E, 0);

    // pool + classify
    k_pool<<<(n + 511) / 512, 256, 0, stream>>>(bufB, batch, sums, cnt, n);
    k_classify<<<1, 128, 0, stream>>>(sums, cnt, Wc, bc, (float*)d_out);
}

// Round 4
// 661.621 us; speedup vs baseline: 1.6826x; 1.0703x over previous
//
#include <hip/hip_runtime.h>
#include <hip/hip_bf16.h>

#define D 128
#define NGRAPH 64
#define SCAN_EPB 2048   // elements per scan block (256 thr * 8)
#define CHUNK 4096      // edges staged in LDS per block in k_fill2
#define BSHIFT 13       // dst-bucket = dst >> 13 (8192 nodes/bucket, ~1MB csr window)
#define SHSHIFT 13      // src-shard = src >> 13 (13 shards of 8192 nodes, 2MB bf16 each)
#define SHPAD 16        // counters per node (13 shards padded to 16)

__device__ __forceinline__ unsigned short f2bf(float f) {
    union { float f; unsigned int i; } u; u.f = f;
    unsigned int r = u.i + 0x7fffu + ((u.i >> 16) & 1u);   // round-to-nearest-even
    return (unsigned short)(r >> 16);
}
__device__ __forceinline__ float2 bf2_to_f2(unsigned int u) {
    union { unsigned int i; float f; } a, b;
    a.i = u << 16;            // low ushort  = element 0
    b.i = u & 0xffff0000u;    // high ushort = element 1
    return make_float2(a.f, b.f);
}

// ---------------- CSR build ----------------
// counters: deg[(dst<<4) | (src>>SHSHIFT)] -> csr segments ordered by src-shard
// rank u8: per-(dst,shard) counter, lambda~2, overflow impossible in practice.

__global__ __launch_bounds__(256) void k_count(const int* __restrict__ src,
                                               const int* __restrict__ dst,
                                               int* __restrict__ deg,
                                               unsigned char* __restrict__ rank, int E) {
    int i = (blockIdx.x * blockDim.x + threadIdx.x) * 4;
    int stride = gridDim.x * blockDim.x * 4;
    for (; i < E; i += stride) {
        if (i + 3 < E) {
            int4 d4 = *(const int4*)&dst[i];
            int4 s4 = *(const int4*)&src[i];
            int r0 = atomicAdd(&deg[(d4.x << 4) | (s4.x >> SHSHIFT)], 1);
            int r1 = atomicAdd(&deg[(d4.y << 4) | (s4.y >> SHSHIFT)], 1);
            int r2 = atomicAdd(&deg[(d4.z << 4) | (s4.z >> SHSHIFT)], 1);
            int r3 = atomicAdd(&deg[(d4.w << 4) | (s4.w >> SHSHIFT)], 1);
            unsigned pack = (unsigned)(r0 & 0xff) | ((unsigned)(r1 & 0xff) << 8) |
                            ((unsigned)(r2 & 0xff) << 16) | ((unsigned)(r3 & 0xff) << 24);
            __builtin_nontemporal_store(pack, (unsigned*)&rank[i]);
        } else {
            for (int j = i; j < E; ++j) {
                int d = dst[j], s = src[j];
                int r = atomicAdd(&deg[(d << 4) | (s >> SHSHIFT)], 1);
                rank[j] = (unsigned char)r;
            }
        }
    }
}

__global__ __launch_bounds__(256) void k_scan_a(const int* __restrict__ deg,
                                                int* __restrict__ offs,
                                                int* __restrict__ bsum, int n16) {
    __shared__ int sdata[256];
    int tid = threadIdx.x;
    int base = blockIdx.x * SCAN_EPB;
    int i0 = base + tid * 8;
    int vals[8];
    int s = 0;
#pragma unroll
    for (int j = 0; j < 8; ++j) {
        int i = i0 + j;
        int d = (i < n16) ? deg[i] : 0;
        vals[j] = s;     // exclusive within thread
        s += d;
    }
    sdata[tid] = s;
    __syncthreads();
    for (int off = 1; off < 256; off <<= 1) {
        int y = (tid >= off) ? sdata[tid - off] : 0;
        __syncthreads();
        sdata[tid] += y;
        __syncthreads();
    }
    int texcl = sdata[tid] - s;
#pragma unroll
    for (int j = 0; j < 8; ++j) {
        int i = i0 + j;
        if (i < n16) offs[i] = texcl + vals[j];
    }
    if (tid == 255) bsum[blockIdx.x] = sdata[255];
}

// parallel exclusive scan over up to 1024 block sums
__global__ __launch_bounds__(1024) void k_scan_b(int* bsum, int nb) {
    __shared__ int sd[1024];
    int tid = threadIdx.x;
    int v = (tid < nb) ? bsum[tid] : 0;
    sd[tid] = v;
    __syncthreads();
    for (int off = 1; off < 1024; off <<= 1) {
        int y = (tid >= off) ? sd[tid - off] : 0;
        __syncthreads();
        sd[tid] += y;
        __syncthreads();
    }
    if (tid < nb) bsum[tid] = sd[tid] - v;   // exclusive
}

// offs += block base (over n*16 counters); dinv from per-node deg sum
__global__ __launch_bounds__(256) void k_finalize(int* __restrict__ offs,
                                                  const int* __restrict__ bsum,
                                                  const int* __restrict__ deg,
                                                  float* __restrict__ dinv, int n) {
    int i = blockIdx.x * blockDim.x + threadIdx.x;
    int n16 = n * SHPAD;
    if (i >= n16) return;
    offs[i] += bsum[i / SCAN_EPB];
    if ((i & 15) == 0) {
        const int4* dp = (const int4*)&deg[i];
        int4 a = dp[0], b = dp[1], c = dp[2], d = dp[3];
        int tot = a.x + a.y + a.z + a.w + b.x + b.y + b.z + b.w +
                  c.x + c.y + c.z + c.w + d.x + d.y + d.z + d.w;
        dinv[i >> 4] = rsqrtf((float)(tot + 1));
    }
}

// bucketed, atomic-free CSR fill; position = offs[(d<<4)|shard(src)] + rank
__global__ __launch_bounds__(256) void k_fill2(const int* __restrict__ src,
                                               const int* __restrict__ dst,
                                               const unsigned char* __restrict__ rank,
                                               const int* __restrict__ offs,
                                               int* __restrict__ csr,
                                               int E, int nbuckets) {
    __shared__ int sdst[CHUNK];
    __shared__ int ssrc[CHUNK];
    __shared__ unsigned char srank[CHUNK];
    int base = blockIdx.x * CHUNK;
    int cnt = min(CHUNK, E - base);
    for (int j = threadIdx.x; j < cnt; j += 256) {
        sdst[j] = __builtin_nontemporal_load(&dst[base + j]);
        ssrc[j] = __builtin_nontemporal_load(&src[base + j]);
    }
    for (int j = threadIdx.x * 4; j < cnt; j += 1024) {
        *(unsigned*)&srank[j] = __builtin_nontemporal_load((const unsigned*)&rank[base + j]);
    }
    __syncthreads();
    for (int p = 0; p < nbuckets; ++p) {
        for (int j = threadIdx.x; j < cnt; j += 256) {
            int d = sdst[j];
            if ((d >> BSHIFT) == p) {
                int s = ssrc[j];
                csr[offs[(d << 4) | (s >> SHSHIFT)] + srank[j]] = s;
            }
        }
        __syncthreads();   // keep the block's waves in lockstep per bucket
    }
}

// ---------------- dense GEMM: H = X @ W  (M x 128 @ 128 x 128, fp32 in, bf16 out)

#define GBM 64
#define GBK 32
__global__ __launch_bounds__(256) void k_gemm128(const float* __restrict__ X,
                                                 const float* __restrict__ W,
                                                 unsigned short* __restrict__ H, int nrows) {
    __shared__ float xs[GBM][GBK + 1];
    __shared__ float ws[GBK][D];
    int tid = threadIdx.x;
    int tc = tid & 31;   // col group: cols tc*4 .. +3
    int tr = tid >> 5;   // row group: rows tr*8 .. +7
    int m0 = blockIdx.x * GBM;
    float acc[8][4] = {};
    for (int kk = 0; kk < D; kk += GBK) {
        for (int i = tid; i < GBM * GBK; i += 256) {
            int r = i >> 5, c = i & 31;
            int gr = m0 + r;
            xs[r][c] = (gr < nrows) ? X[(size_t)gr * D + kk + c] : 0.f;
        }
        for (int i = tid; i < GBK * D; i += 256) {
            int r = i >> 7, c = i & 127;
            ws[r][c] = W[(size_t)(kk + r) * D + c];
        }
        __syncthreads();
#pragma unroll 4
        for (int k = 0; k < GBK; ++k) {
            float a[8];
#pragma unroll
            for (int ri = 0; ri < 8; ++ri) a[ri] = xs[tr * 8 + ri][k];
            float4 bv = *(const float4*)&ws[k][tc * 4];
            float b[4] = {bv.x, bv.y, bv.z, bv.w};
#pragma unroll
            for (int ri = 0; ri < 8; ++ri)
#pragma unroll
                for (int ci = 0; ci < 4; ++ci)
                    acc[ri][ci] += a[ri] * b[ci];
        }
        __syncthreads();
    }
#pragma unroll
    for (int ri = 0; ri < 8; ++ri) {
        int gr = m0 + tr * 8 + ri;
        if (gr < nrows) {
            ushort4 v;
            v.x = f2bf(acc[ri][0]); v.y = f2bf(acc[ri][1]);
            v.z = f2bf(acc[ri][2]); v.w = f2bf(acc[ri][3]);
            *(ushort4*)&H[(size_t)gr * D + tc * 4] = v;
        }
    }
}

// ---------------- aggregation: Out[v] = sum_{e: dst=v} H[src]*norm + self + bias
// H bf16 [n][128]; csr segment for v = [offs[v<<4], offs[(v+1)<<4]) (shard-ordered)

__global__ __launch_bounds__(256) void k_agg(const unsigned short* __restrict__ H,
                                             const int* __restrict__ offs,
                                             const int* __restrict__ csr,
                                             const float* __restrict__ dinv,
                                             const float* __restrict__ bias,
                                             float* __restrict__ Out,
                                             int n, int E, int relu) {
    int wid = threadIdx.x >> 6;
    int lane = threadIdx.x & 63;
    int v = blockIdx.x * 4 + wid;
    if (v >= n) return;
    float dv = dinv[v];
    // self loop: norm = dv*dv
    unsigned us = *(const unsigned*)(H + (size_t)v * D + lane * 2);
    float2 hs = bf2_to_f2(us);
    float dv2 = dv * dv;
    float2 acc = make_float2(hs.x * dv2, hs.y * dv2);
    int e = offs[v << 4];
    int eE = (v == n - 1) ? E : offs[(v + 1) << 4];
    for (; e + 3 < eE; e += 4) {
        int s0 = csr[e], s1 = csr[e + 1], s2 = csr[e + 2], s3 = csr[e + 3];
        unsigned u0 = *(const unsigned*)(H + (size_t)s0 * D + lane * 2);
        unsigned u1 = *(const unsigned*)(H + (size_t)s1 * D + lane * 2);
        unsigned u2 = *(const unsigned*)(H + (size_t)s2 * D + lane * 2);
        unsigned u3 = *(const unsigned*)(H + (size_t)s3 * D + lane * 2);
        float w0 = dinv[s0] * dv, w1 = dinv[s1] * dv;
        float w2 = dinv[s2] * dv, w3 = dinv[s3] * dv;
        float2 h0 = bf2_to_f2(u0), h1 = bf2_to_f2(u1);
        float2 h2 = bf2_to_f2(u2), h3 = bf2_to_f2(u3);
        acc.x += h0.x * w0; acc.y += h0.y * w0;
        acc.x += h1.x * w1; acc.y += h1.y * w1;
        acc.x += h2.x * w2; acc.y += h2.y * w2;
        acc.x += h3.x * w3; acc.y += h3.y * w3;
    }
    for (; e < eE; ++e) {
        int s0 = csr[e];
        float w0 = dinv[s0] * dv;
        unsigned u0 = *(const unsigned*)(H + (size_t)s0 * D + lane * 2);
        float2 h0 = bf2_to_f2(u0);
        acc.x += h0.x * w0; acc.y += h0.y * w0;
    }
    float2 b = ((const float2*)bias)[lane];
    acc.x += b.x; acc.y += b.y;
    if (relu) { acc.x = fmaxf(acc.x, 0.f); acc.y = fmaxf(acc.y, 0.f); }
    *(float2*)(Out + (size_t)v * D + lane * 2) = acc;
}

// ---------------- mean pool (batch sorted) + classifier ----------------

__global__ __launch_bounds__(256) void k_pool(const float* __restrict__ H,
                                              const int* __restrict__ batch,
                                              float* __restrict__ sums,
                                              int* __restrict__ cnt, int n) {
    int wid = threadIdx.x >> 6;
    int lane = threadIdx.x & 63;
    int chunk = blockIdx.x * 4 + wid;   // 128 nodes per wave
    int v0 = chunk * 128;
    if (v0 >= n) return;
    int vend = min(v0 + 128, n);
    int gcur = batch[v0];
    float2 acc = {0.f, 0.f};
    int count = 0;
    for (int v = v0; v < vend; ++v) {
        int g = batch[v];
        if (g != gcur) {
            atomicAdd(&sums[gcur * D + lane * 2], acc.x);
            atomicAdd(&sums[gcur * D + lane * 2 + 1], acc.y);
            if (lane == 0) atomicAdd(&cnt[gcur], count);
            acc.x = acc.y = 0.f; count = 0; gcur = g;
        }
        float2 hv = *(const float2*)(H + (size_t)v * D + lane * 2);
        acc.x += hv.x; acc.y += hv.y;
        ++count;
    }
    atomicAdd(&sums[gcur * D + lane * 2], acc.x);
    atomicAdd(&sums[gcur * D + lane * 2 + 1], acc.y);
    if (lane == 0) atomicAdd(&cnt[gcur], count);
}

__global__ void k_classify(const float* __restrict__ sums, const int* __restrict__ cnt,
                           const float* __restrict__ Wc, const float* __restrict__ bc,
                           float* __restrict__ out) {
    int t = threadIdx.x;         // 128 threads: t = g*2 + c
    if (t >= NGRAPH * 2) return;
    int g = t >> 1, c = t & 1;
    float inv = 1.0f / fmaxf((float)cnt[g], 1.0f);
    float acc = 0.f;
    for (int k = 0; k < D; ++k) acc += sums[g * D + k] * Wc[k * 2 + c];
    out[t] = acc * inv + bc[c];
}

// ---------------- launch ----------------

extern "C" void kernel_launch(void* const* d_in, const int* in_sizes, int n_in,
                              void* d_out, int out_size, void* d_ws, size_t ws_size,
                              hipStream_t stream) {
    const float* x    = (const float*)d_in[0];
    const int*   ei   = (const int*)d_in[1];
    const int*   batch= (const int*)d_in[2];
    const float* W1   = (const float*)d_in[3];
    const float* b1   = (const float*)d_in[4];
    const float* W2   = (const float*)d_in[5];
    const float* b2   = (const float*)d_in[6];
    const float* Wc   = (const float*)d_in[7];
    const float* bc   = (const float*)d_in[8];

    const int n = in_sizes[0] / D;       // 100000
    const int E = in_sizes[1] / 2;       // 3200000
    const int* src = ei;
    const int* dst = ei + E;
    const int n16 = n * SHPAD;

    // workspace carve-up (256B aligned)
    char* ws = (char*)d_ws;
    size_t off = 0;
    auto carve = [&](size_t bytes) -> char* {
        char* p = ws + off;
        off = (off + bytes + 255) & ~(size_t)255;
        return p;
    };
    unsigned short* bufBF = (unsigned short*)carve((size_t)n * D * 2);  // GEMM out (bf16)
    float* bufB   = (float*)carve((size_t)n * D * 4);                   // agg out (fp32)
    int*   csr    = (int*)  carve((size_t)E * 4);
    unsigned char* rank = (unsigned char*)carve((size_t)E);
    int*   deg    = (int*)  carve((size_t)n16 * 4);
    int*   offs   = (int*)  carve((size_t)n16 * 4);
    float* dinv   = (float*)carve((size_t)n * 4);
    int*   bsum   = (int*)  carve(1024 * 4);
    float* sums   = (float*)carve((size_t)NGRAPH * D * 4 + NGRAPH * 4);
    int*   cnt    = (int*)(sums + NGRAPH * D);

    const int nb = (n16 + SCAN_EPB - 1) / SCAN_EPB;   // 782 <= 1024
    const int nbuckets = (n >> BSHIFT) + 1;           // 13 for n=100000

    hipMemsetAsync(deg, 0, (size_t)n16 * 4, stream);
    hipMemsetAsync(sums, 0, (size_t)NGRAPH * D * 4 + NGRAPH * 4, stream);

    k_count<<<(E / 4 + 255) / 256, 256, 0, stream>>>(src, dst, deg, rank, E);
    k_scan_a<<<nb, 256, 0, stream>>>(deg, offs, bsum, n16);
    k_scan_b<<<1, 1024, 0, stream>>>(bsum, nb);
    k_finalize<<<(n16 + 255) / 256, 256, 0, stream>>>(offs, bsum, deg, dinv, n);
    k_fill2<<<(E + CHUNK - 1) / CHUNK, 256, 0, stream>>>(src, dst, rank, offs, csr, E, nbuckets);

    // layer 1: h = relu(agg(x @ W1) + b1)
    k_gemm128<<<(n + GBM - 1) / GBM, 256, 0, stream>>>(x, W1, bufBF, n);
    k_agg<<<(n + 3) / 4, 256, 0, stream>>>(bufBF, offs, csr, dinv, b1, bufB, n, E, 1);
    // layer 2: h2 = agg(h1 @ W2) + b2
    k_gemm128<<<(n + GBM - 1) / GBM, 256, 0, stream>>>(bufB, W2, bufBF, n);
    k_agg<<<(n + 3) / 4, 256, 0, stream>>>(bufBF, offs, csr, dinv, b2, bufB, n, E, 0);

    // pool + classify
    k_pool<<<(n + 511) / 512, 256, 0, stream>>>(bufB, batch, sums, cnt, n);
    k_classify<<<1, 128, 0, stream>>>(sums, cnt, Wc, bc, (float*)d_out);
}